// Round 17
// baseline (341.220 us; speedup 1.0000x reference)
//
#include <hip/hip_runtime.h>

#define B_SZ 16
#define L_SZ 2048
#define DIN 64
#define H_SZ 256
#define NH 32
#define NL 4
#define TC 64
#define NTC 32
#define TCP 32
#define YROW (H_SZ + 8)

typedef __attribute__((ext_vector_type(8))) __bf16 bf16x8;
typedef __attribute__((ext_vector_type(4))) float f32x4;

__device__ __forceinline__ unsigned short f2b(float f) {
  unsigned int u = __builtin_bit_cast(unsigned int, f);
  unsigned int r = u + 0x7fffu + ((u >> 16) & 1u);  // RNE (no NaN inputs here)
  return (unsigned short)(r >> 16);
}
__device__ __forceinline__ float b2f(unsigned short u) {
  unsigned int v = ((unsigned int)u) << 16;
  return __builtin_bit_cast(float, v);
}
__device__ __forceinline__ float gelu_exact(float v) {
  return 0.5f * v * (1.f + erff(v * 0.70710678118654752f));
}
// 16B-granule XOR swizzle for yt
__device__ __forceinline__ int yswz(int row, int col) {
  return (row * YROW + col) ^ (((row >> 3) & 7) << 3);
}

// ---------------- encoder as compensated MFMA GEMM ----------------
__launch_bounds__(512, 4)
__global__ void k_encoder(const float* __restrict__ x, const float* __restrict__ w,
                          const float* __restrict__ bias, float* __restrict__ hbuf) {
  __shared__ __align__(16) unsigned short Wh[128][72];
  __shared__ __align__(16) unsigned short Wl[128][72];
  __shared__ __align__(16) unsigned short xh[128][72];
  __shared__ __align__(16) unsigned short xl[128][72];
  int tid = threadIdx.x;
  int blk = blockIdx.x;           // b(4b) lt(4b) hh(1b)
  int b = blk >> 5;
  int lt = (blk >> 1) & 15;
  int hh = blk & 1;

#pragma unroll
  for (int i = 0; i < 16; ++i) {
    int flat = i * 512 + tid;
    int d = flat >> 7, hl = flat & 127;
    float v = w[d * H_SZ + (hh << 7) + hl];
    unsigned short hv = f2b(v);
    Wh[hl][d] = hv; Wl[hl][d] = f2b(v - b2f(hv));
  }
  {
    int l = tid >> 2, d0 = (tid & 3) << 4;
    const float* src = x + ((size_t)(b * L_SZ + (lt << 7) + l) << 6) + d0;
    unsigned short* dh = &xh[l][d0];
    unsigned short* dl = &xl[l][d0];
#pragma unroll
    for (int jj = 0; jj < 4; ++jj) {
      float4 v = *(const float4*)(src + jj * 4);
      unsigned short h0 = f2b(v.x); dh[jj * 4 + 0] = h0; dl[jj * 4 + 0] = f2b(v.x - b2f(h0));
      unsigned short h1 = f2b(v.y); dh[jj * 4 + 1] = h1; dl[jj * 4 + 1] = f2b(v.y - b2f(h1));
      unsigned short h2 = f2b(v.z); dh[jj * 4 + 2] = h2; dl[jj * 4 + 2] = f2b(v.z - b2f(h2));
      unsigned short h3 = f2b(v.w); dh[jj * 4 + 3] = h3; dl[jj * 4 + 3] = f2b(v.w - b2f(h3));
    }
  }
  __syncthreads();

  int wv = tid >> 6, lane = tid & 63;
  int lrow = lane & 15, lk8 = (lane >> 4) << 3;
  int rsub = (lane >> 4) << 2;
  f32x4 acc[8];
#pragma unroll
  for (int ct = 0; ct < 8; ++ct) acc[ct] = (f32x4){0.f, 0.f, 0.f, 0.f};
#pragma unroll
  for (int kk = 0; kk < 2; ++kk) {
    bf16x8 ah = *(const bf16x8*)&Wh[(wv << 4) + lrow][(kk << 5) + lk8];
    bf16x8 al = *(const bf16x8*)&Wl[(wv << 4) + lrow][(kk << 5) + lk8];
#pragma unroll
    for (int ct = 0; ct < 8; ++ct) {
      bf16x8 bh = *(const bf16x8*)&xh[(ct << 4) + lrow][(kk << 5) + lk8];
      bf16x8 bl = *(const bf16x8*)&xl[(ct << 4) + lrow][(kk << 5) + lk8];
      acc[ct] = __builtin_amdgcn_mfma_f32_16x16x32_bf16(ah, bh, acc[ct], 0, 0, 0);
      acc[ct] = __builtin_amdgcn_mfma_f32_16x16x32_bf16(ah, bl, acc[ct], 0, 0, 0);
      acc[ct] = __builtin_amdgcn_mfma_f32_16x16x32_bf16(al, bh, acc[ct], 0, 0, 0);
    }
  }
  float bi[4];
#pragma unroll
  for (int r = 0; r < 4; ++r) bi[r] = bias[(hh << 7) + (wv << 4) + rsub + r];
#pragma unroll
  for (int ct = 0; ct < 8; ++ct) {
    int lglob = (lt << 7) + (ct << 4) + lrow;
#pragma unroll
    for (int r = 0; r < 4; ++r) {
      int hglob = (hh << 7) + (wv << 4) + rsub + r;
      hbuf[((size_t)(b * H_SZ + hglob) << 11) + lglob] = acc[ct][r] + bi[r];
    }
  }
}

// ---------------- convert w_out to bf16 ----------------
__global__ void k_cvtw(const float* __restrict__ w, unsigned short* __restrict__ wbf, int n) {
  int i = blockIdx.x * 256 + threadIdx.x;
  if (i < n) wbf[i] = f2b(w[i]);
}

// ---------------- precompute per-state params: lr, li, c2r, c2i, lTr, lTi ----------------
__global__ void k_params(const float* __restrict__ log_dt, const float* __restrict__ log_A_real,
                         const float* __restrict__ A_imag, const float* __restrict__ C_re,
                         const float* __restrict__ C_im, float* __restrict__ par) {
  int id = blockIdx.x * 256 + threadIdx.x;  // i*8192 + h*32 + n
  if (id >= NL * H_SZ * NH) return;
  int i = id >> 13;
  int hn = id & 8191;
  int h = hn >> 5;
  float dt = expf(log_dt[i * H_SZ + h]);
  float Ar = -expf(log_A_real[(size_t)i * H_SZ * NH + hn]);
  float Ai = A_imag[(size_t)i * H_SZ * NH + hn];
  float dr = dt * Ar, di = dt * Ai;
  float e = expf(dr), sn, cs;
  sincosf(di, &sn, &cs);
  float lr = e * cs, li = e * sn;
  float eT = expf((float)TC * dr), snT, csT;
  sincosf((float)TC * di, &snT, &csT);
  float Cr = C_re[(size_t)i * H_SZ * NH + hn], Ci = C_im[(size_t)i * H_SZ * NH + hn];
  float wr = lr - 1.f, wi = li;
  float pr = Cr * wr - Ci * wi;
  float pi = Cr * wi + Ci * wr;
  float inv = 2.f / fmaf(Ar, Ar, Ai * Ai);
  float4* p = (float4*)(par + (size_t)id * 8);
  p[0] = make_float4(lr, li, (pr * Ar + pi * Ai) * inv, (pi * Ar - pr * Ai) * inv);
  p[1] = make_float4(eT * csT, eT * snT, 0.f, 0.f);
}

// ---------------- merged SSM kernel (1024 thr, 16 waves): finals+prefix in LDS+conv+GELU ----
__launch_bounds__(1024, 4)
__global__ void k_ssm(const float* __restrict__ hbuf, const float* __restrict__ par,
                      const float* __restrict__ D_skip, unsigned short* __restrict__ yloc) {
  __shared__ __align__(16) unsigned short xbh[256][72];
  __shared__ __align__(16) unsigned short xbl[256][72];
  __shared__ __align__(16) unsigned short Uh[64][72];
  __shared__ __align__(16) unsigned short Ul[64][72];
  __shared__ __align__(16) unsigned short Th[64][72];
  __shared__ __align__(16) unsigned short Tl[64][72];
  __shared__ __align__(16) unsigned short Wh[64][72];
  __shared__ __align__(16) unsigned short Wl[64][72];
  __shared__ float Kc[64];
  int tid = threadIdx.x;
  int h = blockIdx.x;
  float* Wm = (float*)&xbh[0][0];  // [64][66] f32 scratch, dead before x staging

  if (tid < 64) {
    int n = tid >> 1, q = tid & 1;
    const float* pb = par + (size_t)(h * NH + n) * 8;
    float lr = pb[0], li = pb[1], c2r = pb[2], c2i = pb[3];
    float pr = lr, pi = li;  // lam^1
    if (q) {                 // lam^33
      float sr = lr, si = li;
#pragma unroll
      for (int t = 0; t < 5; ++t) { float nr2 = sr * sr - si * si; si = 2.f * sr * si; sr = nr2; }
      pr = sr * lr - si * li; pi = sr * li + si * lr;
    }
    int p = q << 5;
    for (int s = 0; s < 32; ++s, ++p) {
      Wm[p * 66 + 2 * n] = c2r * pr - c2i * pi;
      Wm[p * 66 + 2 * n + 1] = -(c2r * pi + c2i * pr);
      float nr2 = pr * lr - pi * li;
      pi = pr * li + pi * lr;
      pr = nr2;
    }
  }
  __syncthreads();
  if (tid < 64) {
    float kv = 0.f;
    if (tid == 0) {
      for (int n = 0; n < 32; ++n) kv += par[(size_t)(h * NH + n) * 8 + 2];
    } else {
      for (int n = 0; n < 32; ++n) kv += Wm[(tid - 1) * 66 + 2 * n];
    }
    Kc[tid] = kv;
  }
  {
    int base = tid * 4;          // 1024 thr x 4 = 4096 = 64x64
    int row = base >> 6, col0 = base & 63;
#pragma unroll
    for (int e = 0; e < 4; ++e) {
      float v = Wm[row * 66 + col0 + e];
      unsigned short hv = f2b(v);
      Wh[row][col0 + e] = hv; Wl[row][col0 + e] = f2b(v - b2f(hv));
    }
  }
  __syncthreads();
  {
    int base = tid * 4;
    int row = base >> 6, col0 = base & 63;
#pragma unroll
    for (int e = 0; e < 4; ++e) {
      int col = col0 + e;
      float v = (col <= row) ? Kc[row - col] : 0.f;
      unsigned short hv = f2b(v);
      Th[row][col] = hv; Tl[row][col] = f2b(v - b2f(hv));
    }
  }
  if (tid < 64) {
    int n = tid >> 1, q = tid & 1;
    const float* pb = par + (size_t)(h * NH + n) * 8;
    float lr = pb[0], li = pb[1];
    float pr = 1.f, pi = 0.f;
    if (q) {
      float sr = lr, si = li;
#pragma unroll
      for (int t = 0; t < 5; ++t) { float nr2 = sr * sr - si * si; si = 2.f * sr * si; sr = nr2; }
      pr = sr; pi = si;
    }
    int p = q << 5;
    for (int s = 0; s < 32; ++s, ++p) {
      int col = 63 - p;
      unsigned short hr = f2b(pr);
      Uh[2 * n][col] = hr; Ul[2 * n][col] = f2b(pr - b2f(hr));
      unsigned short hm = f2b(pi);
      Uh[2 * n + 1][col] = hm; Ul[2 * n + 1][col] = f2b(pi - b2f(hm));
      float nr2 = pr * lr - pi * li;
      pi = pr * li + pi * lr;
      pr = nr2;
    }
  }

  int wv = tid >> 6, lane = tid & 63;
  int lrow = lane & 15, lk8 = (lane >> 4) << 3;
  int rt = wv >> 2;                // row-tile 0..3
  int cg = wv & 3;                 // col-group 0..3 (4 col-tiles each)
  int rsub = (lane >> 4) << 2;
  float Dh = D_skip[h];

  for (int half = 0; half < 2; ++half) {
    __syncthreads();  // matrices ready / previous half's svec reads done
    // ---- stage x hi/lo (1024 thr: 16 elems each) ----
    {
      int colh = tid >> 2, j0 = (tid & 3) << 4;
      int b = (half << 3) + (colh >> 5), c = colh & 31;
      const float* src = hbuf + ((size_t)(b * H_SZ + h) << 11) + (c << 6) + j0;
      unsigned short* dh = &xbh[colh][j0];
      unsigned short* dl = &xbl[colh][j0];
#pragma unroll
      for (int jj = 0; jj < 4; ++jj) {
        float4 v = *(const float4*)(src + jj * 4);
        unsigned short h0 = f2b(v.x); dh[jj * 4 + 0] = h0; dl[jj * 4 + 0] = f2b(v.x - b2f(h0));
        unsigned short h1 = f2b(v.y); dh[jj * 4 + 1] = h1; dl[jj * 4 + 1] = f2b(v.y - b2f(h1));
        unsigned short h2 = f2b(v.z); dh[jj * 4 + 2] = h2; dl[jj * 4 + 2] = f2b(v.z - b2f(h2));
        unsigned short h3 = f2b(v.w); dh[jj * 4 + 3] = h3; dl[jj * 4 + 3] = f2b(v.w - b2f(h3));
      }
    }
    __syncthreads();
    // ---- U-GEMM: chunk finals (keep in registers) ----
    f32x4 uacc[4];
#pragma unroll
    for (int ct = 0; ct < 4; ++ct) uacc[ct] = (f32x4){0.f, 0.f, 0.f, 0.f};
#pragma unroll
    for (int kk = 0; kk < 2; ++kk) {
      bf16x8 ah = *(const bf16x8*)&Uh[(rt << 4) + lrow][(kk << 5) + lk8];
      bf16x8 al = *(const bf16x8*)&Ul[(rt << 4) + lrow][(kk << 5) + lk8];
#pragma unroll
      for (int ct = 0; ct < 4; ++ct) {
        int col = (((cg << 2) + ct) << 4) + lrow;
        bf16x8 bh = *(const bf16x8*)&xbh[col][(kk << 5) + lk8];
        bf16x8 bl = *(const bf16x8*)&xbl[col][(kk << 5) + lk8];
        uacc[ct] = __builtin_amdgcn_mfma_f32_16x16x32_bf16(ah, bh, uacc[ct], 0, 0, 0);
        uacc[ct] = __builtin_amdgcn_mfma_f32_16x16x32_bf16(ah, bl, uacc[ct], 0, 0, 0);
        uacc[ct] = __builtin_amdgcn_mfma_f32_16x16x32_bf16(al, bh, uacc[ct], 0, 0, 0);
      }
    }
    // ---- T-GEMM (x still staged) ----
    f32x4 acc[4];
#pragma unroll
    for (int ct = 0; ct < 4; ++ct) acc[ct] = (f32x4){0.f, 0.f, 0.f, 0.f};
#pragma unroll
    for (int kk = 0; kk < 2; ++kk) {
      bf16x8 ah = *(const bf16x8*)&Th[(rt << 4) + lrow][(kk << 5) + lk8];
      bf16x8 al = *(const bf16x8*)&Tl[(rt << 4) + lrow][(kk << 5) + lk8];
#pragma unroll
      for (int ct = 0; ct < 4; ++ct) {
        int col = (((cg << 2) + ct) << 4) + lrow;
        bf16x8 bh = *(const bf16x8*)&xbh[col][(kk << 5) + lk8];
        bf16x8 bl = *(const bf16x8*)&xbl[col][(kk << 5) + lk8];
        acc[ct] = __builtin_amdgcn_mfma_f32_16x16x32_bf16(ah, bh, acc[ct], 0, 0, 0);
        acc[ct] = __builtin_amdgcn_mfma_f32_16x16x32_bf16(ah, bl, acc[ct], 0, 0, 0);
        acc[ct] = __builtin_amdgcn_mfma_f32_16x16x32_bf16(al, bh, acc[ct], 0, 0, 0);
      }
    }
    // ---- add D-skip term while x is still staged (x = hi + lo, ~exact) ----
    {
#pragma unroll
      for (int ct = 0; ct < 4; ++ct) {
        int col = (((cg << 2) + ct) << 4) + lrow;
        int row = (rt << 4) + rsub;
        ushort4 xh4 = *(const ushort4*)&xbh[col][row];
        ushort4 xl4 = *(const ushort4*)&xbl[col][row];
        acc[ct][0] = fmaf(Dh, b2f(xh4.x) + b2f(xl4.x), acc[ct][0]);
        acc[ct][1] = fmaf(Dh, b2f(xh4.y) + b2f(xl4.y), acc[ct][1]);
        acc[ct][2] = fmaf(Dh, b2f(xh4.z) + b2f(xl4.z), acc[ct][2]);
        acc[ct][3] = fmaf(Dh, b2f(xh4.w) + b2f(xl4.w), acc[ct][3]);
      }
    }
    __syncthreads();  // all x reads done; xbh/xbl reusable
    // ---- write finals (hi/lo bf16) into xbh/xbl in svec layout [col][2n] ----
    {
      int n0 = (rt << 3) + ((lane >> 4) << 1);
#pragma unroll
      for (int ct = 0; ct < 4; ++ct) {
        int colh = (((cg << 2) + ct) << 4) + lrow;
        ushort4 oh, ol;
        oh.x = f2b(uacc[ct][0]); ol.x = f2b(uacc[ct][0] - b2f(oh.x));
        oh.y = f2b(uacc[ct][1]); ol.y = f2b(uacc[ct][1] - b2f(oh.y));
        oh.z = f2b(uacc[ct][2]); ol.z = f2b(uacc[ct][2] - b2f(oh.z));
        oh.w = f2b(uacc[ct][3]); ol.w = f2b(uacc[ct][3] - b2f(oh.w));
        *(ushort4*)&xbh[colh][2 * n0] = oh;
        *(ushort4*)&xbl[colh][2 * n0] = ol;
      }
    }
    __syncthreads();
    // ---- exclusive prefix in LDS: thread=(b,n); in-place finals -> carries ----
    if (tid < 256) {
      int bb = tid >> 5, n = tid & 31;
      const float* pb = par + (size_t)(h * NH + n) * 8;
      float lTr = pb[4], lTi = pb[5];
      float cr = 0.f, ci = 0.f;
      for (int c = 0; c < NTC; ++c) {
        int col = (bb << 5) + c;
        float fr = b2f(xbh[col][2 * n]) + b2f(xbl[col][2 * n]);
        float fi = b2f(xbh[col][2 * n + 1]) + b2f(xbl[col][2 * n + 1]);
        unsigned short hr = f2b(cr);
        xbh[col][2 * n] = hr; xbl[col][2 * n] = f2b(cr - b2f(hr));
        unsigned short hm = f2b(ci);
        xbh[col][2 * n + 1] = hm; xbl[col][2 * n + 1] = f2b(ci - b2f(hm));
        float nr = fmaf(lTr, cr, fr); nr = fmaf(-lTi, ci, nr);
        float ni = fmaf(lTr, ci, fi); ni = fmaf(lTi, cr, ni);
        cr = nr; ci = ni;
      }
    }
    __syncthreads();
    // ---- W-GEMM (carry contribution), accumulate; gelu; write y bf16 ----
#pragma unroll
    for (int kk = 0; kk < 2; ++kk) {
      bf16x8 ah = *(const bf16x8*)&Wh[(rt << 4) + lrow][(kk << 5) + lk8];
      bf16x8 al = *(const bf16x8*)&Wl[(rt << 4) + lrow][(kk << 5) + lk8];
#pragma unroll
      for (int ct = 0; ct < 4; ++ct) {
        int col = (((cg << 2) + ct) << 4) + lrow;
        bf16x8 bh = *(const bf16x8*)&xbh[col][(kk << 5) + lk8];
        bf16x8 bl = *(const bf16x8*)&xbl[col][(kk << 5) + lk8];
        acc[ct] = __builtin_amdgcn_mfma_f32_16x16x32_bf16(ah, bh, acc[ct], 0, 0, 0);
        acc[ct] = __builtin_amdgcn_mfma_f32_16x16x32_bf16(ah, bl, acc[ct], 0, 0, 0);
        acc[ct] = __builtin_amdgcn_mfma_f32_16x16x32_bf16(al, bh, acc[ct], 0, 0, 0);
      }
    }
#pragma unroll
    for (int ct = 0; ct < 4; ++ct) {
      int colg = (half << 8) + (((cg << 2) + ct) << 4) + lrow;
      ushort4 o;
      o.x = f2b(gelu_exact(acc[ct][0]));
      o.y = f2b(gelu_exact(acc[ct][1]));
      o.z = f2b(gelu_exact(acc[ct][2]));
      o.w = f2b(gelu_exact(acc[ct][3]));
      *(ushort4*)(yloc + (size_t)h * (B_SZ * L_SZ) + (size_t)colg * 64 + (rt << 4) + rsub) = o;
    }
  }
}

// ---------------- post (TC=32, 512 thr, 4 blocks/CU): yt copy + GLU + LN ----------------
__launch_bounds__(512, 4)
__global__ void k_layer2(float* __restrict__ hbuf, const unsigned short* __restrict__ yloc,
                         const unsigned short* __restrict__ wbf,
                         const float* __restrict__ b_out,
                         const float* __restrict__ ln_g, const float* __restrict__ ln_b,
                         float* __restrict__ pooledPart, int last) {
  __shared__ __align__(16) unsigned short yt[TCP * YROW];  // 16896 B
  __shared__ float part[TCP][16][2];                       // 4096 B
  __shared__ float stats[TCP][2];                          // 256 B
  int tid = threadIdx.x;
  int b = blockIdx.x >> 6;
  int c = blockIdx.x & 63;
  int l0 = c << 5;

  // ---- fill: yloc (already gelu'd) -> yt transpose copy ----
  {
    int h = tid >> 1, q = tid & 1;
    const unsigned short* yp2 = yloc + (size_t)h * (B_SZ * L_SZ) + b * L_SZ + l0 + (q << 4);
#pragma unroll
    for (int jj = 0; jj < 16; jj += 4) {
      ushort4 yv = *(const ushort4*)(yp2 + jj);
      int jb = (q << 4) + jj;
      yt[yswz(jb + 0, h)] = yv.x;
      yt[yswz(jb + 1, h)] = yv.y;
      yt[yswz(jb + 2, h)] = yv.z;
      yt[yswz(jb + 3, h)] = yv.w;
    }
  }
  __syncthreads();
  // ---- GLU: 1x1 conv via MFMA (8 waves; wave w owns A rows {w*16, w*16+128}, G +256/+384) ----
  {
    int w = tid >> 6, lane = tid & 63;
    int lrow = lane & 15, lk8 = (lane >> 4) << 3;
    f32x4 accA[4], accG[4];
    f32x4 zed = {0.f, 0.f, 0.f, 0.f};
#pragma unroll
    for (int t = 0; t < 4; ++t) { accA[t] = zed; accG[t] = zed; }
    const unsigned short* wA0 = wbf + ((w << 4) + lrow) * H_SZ;
    const unsigned short* wA1 = wA0 + 128 * H_SZ;
    const unsigned short* wG0 = wA0 + 256 * H_SZ;
    const unsigned short* wG1 = wA0 + 384 * H_SZ;
#pragma unroll
    for (int k0 = 0; k0 < H_SZ; k0 += 32) {
      bf16x8 a0 = *(const bf16x8*)(wA0 + k0 + lk8);
      bf16x8 a1 = *(const bf16x8*)(wA1 + k0 + lk8);
      bf16x8 g0 = *(const bf16x8*)(wG0 + k0 + lk8);
      bf16x8 g1 = *(const bf16x8*)(wG1 + k0 + lk8);
#pragma unroll
      for (int jt = 0; jt < 2; ++jt) {
        bf16x8 bb = *(const bf16x8*)&yt[yswz((jt << 4) + lrow, k0 + lk8)];
        accA[jt]     = __builtin_amdgcn_mfma_f32_16x16x32_bf16(a0, bb, accA[jt], 0, 0, 0);
        accA[2 + jt] = __builtin_amdgcn_mfma_f32_16x16x32_bf16(a1, bb, accA[2 + jt], 0, 0, 0);
        accG[jt]     = __builtin_amdgcn_mfma_f32_16x16x32_bf16(g0, bb, accG[jt], 0, 0, 0);
        accG[2 + jt] = __builtin_amdgcn_mfma_f32_16x16x32_bf16(g1, bb, accG[2 + jt], 0, 0, 0);
      }
    }
    __syncthreads();  // all y reads done before overwrite with z
    int rbase = (lane >> 4) << 2;
    float bA[8], bG[8];
#pragma unroll
    for (int t = 0; t < 2; ++t) {
#pragma unroll
      for (int r = 0; r < 4; ++r) {
        bA[t * 4 + r] = b_out[(w << 4) + t * 128 + rbase + r];
        bG[t * 4 + r] = b_out[256 + (w << 4) + t * 128 + rbase + r];
      }
    }
#pragma unroll
    for (int t = 0; t < 2; ++t) {
#pragma unroll
      for (int jt = 0; jt < 2; ++jt) {
        ushort4 o;
        float a0 = accA[t * 2 + jt][0] + bA[t * 4 + 0], g0 = accG[t * 2 + jt][0] + bG[t * 4 + 0];
        float a1 = accA[t * 2 + jt][1] + bA[t * 4 + 1], g1 = accG[t * 2 + jt][1] + bG[t * 4 + 1];
        float a2 = accA[t * 2 + jt][2] + bA[t * 4 + 2], g2 = accG[t * 2 + jt][2] + bG[t * 4 + 2];
        float a3 = accA[t * 2 + jt][3] + bA[t * 4 + 3], g3 = accG[t * 2 + jt][3] + bG[t * 4 + 3];
        o.x = f2b(a0 / (1.f + expf(-g0)));
        o.y = f2b(a1 / (1.f + expf(-g1)));
        o.z = f2b(a2 / (1.f + expf(-g2)));
        o.w = f2b(a3 / (1.f + expf(-g3)));
        *(ushort4*)&yt[yswz((jt << 4) + lrow, (w << 4) + t * 128 + rbase)] = o;
      }
    }
  }
  __syncthreads();
  // ---- LN stats; v = z + residual ----
  int j = tid & 31, hg = tid >> 5;  // 16 groups of 16 h
  float vreg[16];
  {
    const float* xc = hbuf + (b * H_SZ + (hg << 4)) * L_SZ + l0 + j;
    float s = 0.f, sq = 0.f;
    ushort4 za = *(const ushort4*)&yt[yswz(j, (hg << 4) + 0)];
    ushort4 zb = *(const ushort4*)&yt[yswz(j, (hg << 4) + 4)];
    ushort4 zc = *(const ushort4*)&yt[yswz(j, (hg << 4) + 8)];
    ushort4 zd = *(const ushort4*)&yt[yswz(j, (hg << 4) + 12)];
    unsigned short zz[16] = {za.x, za.y, za.z, za.w, zb.x, zb.y, zb.z, zb.w,
                             zc.x, zc.y, zc.z, zc.w, zd.x, zd.y, zd.z, zd.w};
#pragma unroll
    for (int k = 0; k < 16; ++k) {
      float v = b2f(zz[k]) + xc[(size_t)k * L_SZ];
      vreg[k] = v;
      s += v; sq = fmaf(v, v, sq);
    }
    part[j][hg][0] = s; part[j][hg][1] = sq;
  }
  __syncthreads();
  if (tid < TCP) {
    float s = 0.f, sq = 0.f;
#pragma unroll
    for (int g = 0; g < 16; ++g) { s += part[tid][g][0]; sq += part[tid][g][1]; }
    float mu = s * (1.f / 256.f);
    float var = sq * (1.f / 256.f) - mu * mu;
    stats[tid][0] = mu;
    stats[tid][1] = rsqrtf(var + 1e-5f);
  }
  __syncthreads();
  {
    float mu = stats[j][0], rs = stats[j][1];
    if (!last) {
      float* xo = hbuf + (b * H_SZ + (hg << 4)) * L_SZ + l0 + j;
#pragma unroll
      for (int k = 0; k < 16; ++k) {
        int hh = (hg << 4) + k;
        xo[(size_t)k * L_SZ] = (vreg[k] - mu) * rs * ln_g[hh] + ln_b[hh];
      }
    } else {
#pragma unroll
      for (int k = 0; k < 16; ++k) {
        int hh = (hg << 4) + k;
        yt[yswz(j, hh)] = f2b((vreg[k] - mu) * rs * ln_g[hh] + ln_b[hh]);
      }
      __syncthreads();
      if (tid < H_SZ) {
        float s = 0.f;
        for (int jj = 0; jj < TCP; ++jj) s += b2f(yt[yswz(jj, tid)]);
        pooledPart[(((b << 6) + c) << 8) + tid] = s;
      }
    }
  }
}

// ---------------- pool: reduce 64 chunk-partials per (b,h) ----------------
__global__ void k_pool(const float* __restrict__ pooledPart, float* __restrict__ P) {
  int b = blockIdx.x, hh = threadIdx.x;
  float s = 0.f;
#pragma unroll
  for (int cpart = 0; cpart < 64; ++cpart)
    s += pooledPart[(((b << 6) + cpart) << 8) + hh];
  P[(b << 8) + hh] = s * (1.f / 2048.f);
}

// ---------------- decoder MLP: one block per batch row ----------------
__global__ void k_dec(const float* __restrict__ P,
                      const float* __restrict__ w1, const float* __restrict__ b1,
                      const float* __restrict__ w2, const float* __restrict__ b2,
                      const float* __restrict__ w3, const float* __restrict__ b3,
                      float* __restrict__ out) {
  __shared__ float Pr[256];
  __shared__ float O1[128];
  __shared__ float O2[64];
  int b = blockIdx.x, tid = threadIdx.x;
  Pr[tid] = P[(b << 8) + tid];
  __syncthreads();
  if (tid < 128) {
    float acc = b1[tid];
    for (int d = 0; d < 256; ++d) acc = fmaf(Pr[d], w1[(d << 7) + tid], acc);
    O1[tid] = fmaxf(acc, 0.f);
  }
  __syncthreads();
  if (tid < 64) {
    float acc = b2[tid];
    for (int d = 0; d < 128; ++d) acc = fmaf(O1[d], w2[(d << 6) + tid], acc);
    O2[tid] = fmaxf(acc, 0.f);
  }
  __syncthreads();
  if (tid < 32) {
    float acc = b3[tid];
    for (int d = 0; d < 64; ++d) acc = fmaf(O2[d], w3[(d << 5) + tid], acc);
    out[(b << 5) + tid] = acc;
  }
}

extern "C" void kernel_launch(void* const* d_in, const int* in_sizes, int n_in,
                              void* d_out, int out_size, void* d_ws, size_t ws_size,
                              hipStream_t stream) {
  const float* x          = (const float*)d_in[0];
  const float* enc_w      = (const float*)d_in[1];
  const float* enc_b      = (const float*)d_in[2];
  const float* log_dt     = (const float*)d_in[3];
  const float* C_re       = (const float*)d_in[4];
  const float* C_im       = (const float*)d_in[5];
  const float* log_A_real = (const float*)d_in[6];
  const float* A_imag     = (const float*)d_in[7];
  const float* D_skip     = (const float*)d_in[8];
  const float* w_out      = (const float*)d_in[9];
  const float* b_out      = (const float*)d_in[10];
  const float* ln_g       = (const float*)d_in[11];
  const float* ln_b       = (const float*)d_in[12];
  const float* dw1        = (const float*)d_in[13];
  const float* db1        = (const float*)d_in[14];
  const float* dw2        = (const float*)d_in[15];
  const float* db2        = (const float*)d_in[16];
  const float* dw3        = (const float*)d_in[17];
  const float* db3        = (const float*)d_in[18];

  char* ws = (char*)d_ws;
  float* hbuf = (float*)ws;                                  // 33,554,432 B
  unsigned short* yloc = (unsigned short*)(ws + 33554432);   // 16,777,216 B (bf16)
  unsigned short* wbf = (unsigned short*)(ws + 50331648);    //  1,048,576 B
  float* par = (float*)(ws + 51380224);                      //  1,048,576 B
  float* pooledPart = (float*)(ws + 52428800);               //  1,048,576 B
  float* P = (float*)(ws + 53477376);                        //     16,384 B

  k_encoder<<<512, 512, 0, stream>>>(x, enc_w, enc_b, hbuf);
  k_cvtw<<<2048, 256, 0, stream>>>(w_out, wbf, NL * 512 * H_SZ);
  k_params<<<128, 256, 0, stream>>>(log_dt, log_A_real, A_imag, C_re, C_im, par);
  const size_t PAR_STRIDE = (size_t)H_SZ * NH * 8;
  for (int i = 0; i < NL; ++i) {
    const float* pari = par + i * PAR_STRIDE;
    k_ssm<<<256, 1024, 0, stream>>>(hbuf, pari, D_skip + i * H_SZ, yloc);
    k_layer2<<<1024, 512, 0, stream>>>(hbuf, yloc,
                                       wbf + i * 512 * H_SZ, b_out + i * 512,
                                       ln_g + i * H_SZ, ln_b + i * H_SZ,
                                       pooledPart, (i == NL - 1) ? 1 : 0);
  }
  k_pool<<<16, 256, 0, stream>>>(pooledPart, P);
  k_dec<<<16, 256, 0, stream>>>(P, dw1, db1, dw2, db2, dw3, db3, (float*)d_out);
}

// Round 18
// 307.555 us; speedup vs baseline: 1.1095x; 1.1095x over previous
//
#include <hip/hip_runtime.h>

#define B_SZ 16
#define L_SZ 2048
#define DIN 64
#define H_SZ 256
#define NH 32
#define NL 4
#define TC 64
#define NTC 32
#define YROW (H_SZ + 8)

typedef __attribute__((ext_vector_type(8))) __bf16 bf16x8;
typedef __attribute__((ext_vector_type(4))) float f32x4;

__device__ __forceinline__ unsigned short f2b(float f) {
  unsigned int u = __builtin_bit_cast(unsigned int, f);
  unsigned int r = u + 0x7fffu + ((u >> 16) & 1u);  // RNE (no NaN inputs here)
  return (unsigned short)(r >> 16);
}
__device__ __forceinline__ float b2f(unsigned short u) {
  unsigned int v = ((unsigned int)u) << 16;
  return __builtin_bit_cast(float, v);
}
__device__ __forceinline__ float gelu_exact(float v) {
  return 0.5f * v * (1.f + erff(v * 0.70710678118654752f));
}
// 16B-granule XOR swizzle for yt
__device__ __forceinline__ int yswz(int row, int col) {
  return (row * YROW + col) ^ (((row >> 3) & 7) << 3);
}

// ---------------- encoder as compensated MFMA GEMM ----------------
__launch_bounds__(512, 4)
__global__ void k_encoder(const float* __restrict__ x, const float* __restrict__ w,
                          const float* __restrict__ bias, float* __restrict__ hbuf) {
  __shared__ __align__(16) unsigned short Wh[128][72];
  __shared__ __align__(16) unsigned short Wl[128][72];
  __shared__ __align__(16) unsigned short xh[128][72];
  __shared__ __align__(16) unsigned short xl[128][72];
  int tid = threadIdx.x;
  int blk = blockIdx.x;           // b(4b) lt(4b) hh(1b)
  int b = blk >> 5;
  int lt = (blk >> 1) & 15;
  int hh = blk & 1;

#pragma unroll
  for (int i = 0; i < 16; ++i) {
    int flat = i * 512 + tid;
    int d = flat >> 7, hl = flat & 127;
    float v = w[d * H_SZ + (hh << 7) + hl];
    unsigned short hv = f2b(v);
    Wh[hl][d] = hv; Wl[hl][d] = f2b(v - b2f(hv));
  }
  {
    int l = tid >> 2, d0 = (tid & 3) << 4;
    const float* src = x + ((size_t)(b * L_SZ + (lt << 7) + l) << 6) + d0;
    unsigned short* dh = &xh[l][d0];
    unsigned short* dl = &xl[l][d0];
#pragma unroll
    for (int jj = 0; jj < 4; ++jj) {
      float4 v = *(const float4*)(src + jj * 4);
      unsigned short h0 = f2b(v.x); dh[jj * 4 + 0] = h0; dl[jj * 4 + 0] = f2b(v.x - b2f(h0));
      unsigned short h1 = f2b(v.y); dh[jj * 4 + 1] = h1; dl[jj * 4 + 1] = f2b(v.y - b2f(h1));
      unsigned short h2 = f2b(v.z); dh[jj * 4 + 2] = h2; dl[jj * 4 + 2] = f2b(v.z - b2f(h2));
      unsigned short h3 = f2b(v.w); dh[jj * 4 + 3] = h3; dl[jj * 4 + 3] = f2b(v.w - b2f(h3));
    }
  }
  __syncthreads();

  int wv = tid >> 6, lane = tid & 63;
  int lrow = lane & 15, lk8 = (lane >> 4) << 3;
  int rsub = (lane >> 4) << 2;
  f32x4 acc[8];
#pragma unroll
  for (int ct = 0; ct < 8; ++ct) acc[ct] = (f32x4){0.f, 0.f, 0.f, 0.f};
#pragma unroll
  for (int kk = 0; kk < 2; ++kk) {
    bf16x8 ah = *(const bf16x8*)&Wh[(wv << 4) + lrow][(kk << 5) + lk8];
    bf16x8 al = *(const bf16x8*)&Wl[(wv << 4) + lrow][(kk << 5) + lk8];
#pragma unroll
    for (int ct = 0; ct < 8; ++ct) {
      bf16x8 bh = *(const bf16x8*)&xh[(ct << 4) + lrow][(kk << 5) + lk8];
      bf16x8 bl = *(const bf16x8*)&xl[(ct << 4) + lrow][(kk << 5) + lk8];
      acc[ct] = __builtin_amdgcn_mfma_f32_16x16x32_bf16(ah, bh, acc[ct], 0, 0, 0);
      acc[ct] = __builtin_amdgcn_mfma_f32_16x16x32_bf16(ah, bl, acc[ct], 0, 0, 0);
      acc[ct] = __builtin_amdgcn_mfma_f32_16x16x32_bf16(al, bh, acc[ct], 0, 0, 0);
    }
  }
  float bi[4];
#pragma unroll
  for (int r = 0; r < 4; ++r) bi[r] = bias[(hh << 7) + (wv << 4) + rsub + r];
#pragma unroll
  for (int ct = 0; ct < 8; ++ct) {
    int lglob = (lt << 7) + (ct << 4) + lrow;
#pragma unroll
    for (int r = 0; r < 4; ++r) {
      int hglob = (hh << 7) + (wv << 4) + rsub + r;
      hbuf[((size_t)(b * H_SZ + hglob) << 11) + lglob] = acc[ct][r] + bi[r];
    }
  }
}

// ---------------- convert w_out to bf16 ----------------
__global__ void k_cvtw(const float* __restrict__ w, unsigned short* __restrict__ wbf, int n) {
  int i = blockIdx.x * 256 + threadIdx.x;
  if (i < n) wbf[i] = f2b(w[i]);
}

// ---------------- precompute per-state params: lr, li, c2r, c2i, lTr, lTi ----------------
__global__ void k_params(const float* __restrict__ log_dt, const float* __restrict__ log_A_real,
                         const float* __restrict__ A_imag, const float* __restrict__ C_re,
                         const float* __restrict__ C_im, float* __restrict__ par) {
  int id = blockIdx.x * 256 + threadIdx.x;  // i*8192 + h*32 + n
  if (id >= NL * H_SZ * NH) return;
  int i = id >> 13;
  int hn = id & 8191;
  int h = hn >> 5;
  float dt = expf(log_dt[i * H_SZ + h]);
  float Ar = -expf(log_A_real[(size_t)i * H_SZ * NH + hn]);
  float Ai = A_imag[(size_t)i * H_SZ * NH + hn];
  float dr = dt * Ar, di = dt * Ai;
  float e = expf(dr), sn, cs;
  sincosf(di, &sn, &cs);
  float lr = e * cs, li = e * sn;
  float eT = expf((float)TC * dr), snT, csT;
  sincosf((float)TC * di, &snT, &csT);
  float Cr = C_re[(size_t)i * H_SZ * NH + hn], Ci = C_im[(size_t)i * H_SZ * NH + hn];
  float wr = lr - 1.f, wi = li;
  float pr = Cr * wr - Ci * wi;
  float pi = Cr * wi + Ci * wr;
  float inv = 2.f / fmaf(Ar, Ar, Ai * Ai);
  float4* p = (float4*)(par + (size_t)id * 8);
  p[0] = make_float4(lr, li, (pr * Ar + pi * Ai) * inv, (pi * Ar - pr * Ai) * inv);
  p[1] = make_float4(eT * csT, eT * snT, 0.f, 0.f);
}

// ---------------- merged SSM kernel (1024 thr, 16 waves): finals+prefix in LDS+conv+GELU ----
__launch_bounds__(1024, 4)
__global__ void k_ssm(const float* __restrict__ hbuf, const float* __restrict__ par,
                      const float* __restrict__ D_skip, unsigned short* __restrict__ yloc) {
  __shared__ __align__(16) unsigned short xbh[256][72];
  __shared__ __align__(16) unsigned short xbl[256][72];
  __shared__ __align__(16) unsigned short Uh[64][72];
  __shared__ __align__(16) unsigned short Ul[64][72];
  __shared__ __align__(16) unsigned short Th[64][72];
  __shared__ __align__(16) unsigned short Tl[64][72];
  __shared__ __align__(16) unsigned short Wh[64][72];
  __shared__ __align__(16) unsigned short Wl[64][72];
  __shared__ float Kc[64];
  int tid = threadIdx.x;
  int h = blockIdx.x;
  float* Wm = (float*)&xbh[0][0];  // [64][66] f32 scratch, dead before x staging

  if (tid < 64) {
    int n = tid >> 1, q = tid & 1;
    const float* pb = par + (size_t)(h * NH + n) * 8;
    float lr = pb[0], li = pb[1], c2r = pb[2], c2i = pb[3];
    float pr = lr, pi = li;  // lam^1
    if (q) {                 // lam^33
      float sr = lr, si = li;
#pragma unroll
      for (int t = 0; t < 5; ++t) { float nr2 = sr * sr - si * si; si = 2.f * sr * si; sr = nr2; }
      pr = sr * lr - si * li; pi = sr * li + si * lr;
    }
    int p = q << 5;
    for (int s = 0; s < 32; ++s, ++p) {
      Wm[p * 66 + 2 * n] = c2r * pr - c2i * pi;
      Wm[p * 66 + 2 * n + 1] = -(c2r * pi + c2i * pr);
      float nr2 = pr * lr - pi * li;
      pi = pr * li + pi * lr;
      pr = nr2;
    }
  }
  __syncthreads();
  if (tid < 64) {
    float kv = 0.f;
    if (tid == 0) {
      for (int n = 0; n < 32; ++n) kv += par[(size_t)(h * NH + n) * 8 + 2];
    } else {
      for (int n = 0; n < 32; ++n) kv += Wm[(tid - 1) * 66 + 2 * n];
    }
    Kc[tid] = kv;
  }
  {
    int base = tid * 4;          // 1024 thr x 4 = 4096 = 64x64
    int row = base >> 6, col0 = base & 63;
#pragma unroll
    for (int e = 0; e < 4; ++e) {
      float v = Wm[row * 66 + col0 + e];
      unsigned short hv = f2b(v);
      Wh[row][col0 + e] = hv; Wl[row][col0 + e] = f2b(v - b2f(hv));
    }
  }
  __syncthreads();
  {
    int base = tid * 4;
    int row = base >> 6, col0 = base & 63;
#pragma unroll
    for (int e = 0; e < 4; ++e) {
      int col = col0 + e;
      float v = (col <= row) ? Kc[row - col] : 0.f;
      unsigned short hv = f2b(v);
      Th[row][col] = hv; Tl[row][col] = f2b(v - b2f(hv));
    }
  }
  if (tid < 64) {
    int n = tid >> 1, q = tid & 1;
    const float* pb = par + (size_t)(h * NH + n) * 8;
    float lr = pb[0], li = pb[1];
    float pr = 1.f, pi = 0.f;
    if (q) {
      float sr = lr, si = li;
#pragma unroll
      for (int t = 0; t < 5; ++t) { float nr2 = sr * sr - si * si; si = 2.f * sr * si; sr = nr2; }
      pr = sr; pi = si;
    }
    int p = q << 5;
    for (int s = 0; s < 32; ++s, ++p) {
      int col = 63 - p;
      unsigned short hr = f2b(pr);
      Uh[2 * n][col] = hr; Ul[2 * n][col] = f2b(pr - b2f(hr));
      unsigned short hm = f2b(pi);
      Uh[2 * n + 1][col] = hm; Ul[2 * n + 1][col] = f2b(pi - b2f(hm));
      float nr2 = pr * lr - pi * li;
      pi = pr * li + pi * lr;
      pr = nr2;
    }
  }

  int wv = tid >> 6, lane = tid & 63;
  int lrow = lane & 15, lk8 = (lane >> 4) << 3;
  int rt = wv >> 2;                // row-tile 0..3
  int cg = wv & 3;                 // col-group 0..3 (4 col-tiles each)
  int rsub = (lane >> 4) << 2;
  float Dh = D_skip[h];

  for (int half = 0; half < 2; ++half) {
    __syncthreads();  // matrices ready / previous half's svec reads done
    // ---- stage x hi/lo (1024 thr: 16 elems each) ----
    {
      int colh = tid >> 2, j0 = (tid & 3) << 4;
      int b = (half << 3) + (colh >> 5), c = colh & 31;
      const float* src = hbuf + ((size_t)(b * H_SZ + h) << 11) + (c << 6) + j0;
      unsigned short* dh = &xbh[colh][j0];
      unsigned short* dl = &xbl[colh][j0];
#pragma unroll
      for (int jj = 0; jj < 4; ++jj) {
        float4 v = *(const float4*)(src + jj * 4);
        unsigned short h0 = f2b(v.x); dh[jj * 4 + 0] = h0; dl[jj * 4 + 0] = f2b(v.x - b2f(h0));
        unsigned short h1 = f2b(v.y); dh[jj * 4 + 1] = h1; dl[jj * 4 + 1] = f2b(v.y - b2f(h1));
        unsigned short h2 = f2b(v.z); dh[jj * 4 + 2] = h2; dl[jj * 4 + 2] = f2b(v.z - b2f(h2));
        unsigned short h3 = f2b(v.w); dh[jj * 4 + 3] = h3; dl[jj * 4 + 3] = f2b(v.w - b2f(h3));
      }
    }
    __syncthreads();
    // ---- U-GEMM: chunk finals (keep in registers) ----
    f32x4 uacc[4];
#pragma unroll
    for (int ct = 0; ct < 4; ++ct) uacc[ct] = (f32x4){0.f, 0.f, 0.f, 0.f};
#pragma unroll
    for (int kk = 0; kk < 2; ++kk) {
      bf16x8 ah = *(const bf16x8*)&Uh[(rt << 4) + lrow][(kk << 5) + lk8];
      bf16x8 al = *(const bf16x8*)&Ul[(rt << 4) + lrow][(kk << 5) + lk8];
#pragma unroll
      for (int ct = 0; ct < 4; ++ct) {
        int col = (((cg << 2) + ct) << 4) + lrow;
        bf16x8 bh = *(const bf16x8*)&xbh[col][(kk << 5) + lk8];
        bf16x8 bl = *(const bf16x8*)&xbl[col][(kk << 5) + lk8];
        uacc[ct] = __builtin_amdgcn_mfma_f32_16x16x32_bf16(ah, bh, uacc[ct], 0, 0, 0);
        uacc[ct] = __builtin_amdgcn_mfma_f32_16x16x32_bf16(ah, bl, uacc[ct], 0, 0, 0);
        uacc[ct] = __builtin_amdgcn_mfma_f32_16x16x32_bf16(al, bh, uacc[ct], 0, 0, 0);
      }
    }
    // ---- T-GEMM (x still staged) ----
    f32x4 acc[4];
#pragma unroll
    for (int ct = 0; ct < 4; ++ct) acc[ct] = (f32x4){0.f, 0.f, 0.f, 0.f};
#pragma unroll
    for (int kk = 0; kk < 2; ++kk) {
      bf16x8 ah = *(const bf16x8*)&Th[(rt << 4) + lrow][(kk << 5) + lk8];
      bf16x8 al = *(const bf16x8*)&Tl[(rt << 4) + lrow][(kk << 5) + lk8];
#pragma unroll
      for (int ct = 0; ct < 4; ++ct) {
        int col = (((cg << 2) + ct) << 4) + lrow;
        bf16x8 bh = *(const bf16x8*)&xbh[col][(kk << 5) + lk8];
        bf16x8 bl = *(const bf16x8*)&xbl[col][(kk << 5) + lk8];
        acc[ct] = __builtin_amdgcn_mfma_f32_16x16x32_bf16(ah, bh, acc[ct], 0, 0, 0);
        acc[ct] = __builtin_amdgcn_mfma_f32_16x16x32_bf16(ah, bl, acc[ct], 0, 0, 0);
        acc[ct] = __builtin_amdgcn_mfma_f32_16x16x32_bf16(al, bh, acc[ct], 0, 0, 0);
      }
    }
    // ---- add D-skip term while x is still staged (x = hi + lo, ~exact) ----
    {
#pragma unroll
      for (int ct = 0; ct < 4; ++ct) {
        int col = (((cg << 2) + ct) << 4) + lrow;
        int row = (rt << 4) + rsub;
        ushort4 xh4 = *(const ushort4*)&xbh[col][row];
        ushort4 xl4 = *(const ushort4*)&xbl[col][row];
        acc[ct][0] = fmaf(Dh, b2f(xh4.x) + b2f(xl4.x), acc[ct][0]);
        acc[ct][1] = fmaf(Dh, b2f(xh4.y) + b2f(xl4.y), acc[ct][1]);
        acc[ct][2] = fmaf(Dh, b2f(xh4.z) + b2f(xl4.z), acc[ct][2]);
        acc[ct][3] = fmaf(Dh, b2f(xh4.w) + b2f(xl4.w), acc[ct][3]);
      }
    }
    __syncthreads();  // all x reads done; xbh/xbl reusable
    // ---- write finals (hi/lo bf16) into xbh/xbl in svec layout [col][2n] ----
    {
      int n0 = (rt << 3) + ((lane >> 4) << 1);
#pragma unroll
      for (int ct = 0; ct < 4; ++ct) {
        int colh = (((cg << 2) + ct) << 4) + lrow;
        ushort4 oh, ol;
        oh.x = f2b(uacc[ct][0]); ol.x = f2b(uacc[ct][0] - b2f(oh.x));
        oh.y = f2b(uacc[ct][1]); ol.y = f2b(uacc[ct][1] - b2f(oh.y));
        oh.z = f2b(uacc[ct][2]); ol.z = f2b(uacc[ct][2] - b2f(oh.z));
        oh.w = f2b(uacc[ct][3]); ol.w = f2b(uacc[ct][3] - b2f(oh.w));
        *(ushort4*)&xbh[colh][2 * n0] = oh;
        *(ushort4*)&xbl[colh][2 * n0] = ol;
      }
    }
    __syncthreads();
    // ---- exclusive prefix in LDS: thread=(b,n); in-place finals -> carries ----
    if (tid < 256) {
      int bb = tid >> 5, n = tid & 31;
      const float* pb = par + (size_t)(h * NH + n) * 8;
      float lTr = pb[4], lTi = pb[5];
      float cr = 0.f, ci = 0.f;
      for (int c = 0; c < NTC; ++c) {
        int col = (bb << 5) + c;
        float fr = b2f(xbh[col][2 * n]) + b2f(xbl[col][2 * n]);
        float fi = b2f(xbh[col][2 * n + 1]) + b2f(xbl[col][2 * n + 1]);
        unsigned short hr = f2b(cr);
        xbh[col][2 * n] = hr; xbl[col][2 * n] = f2b(cr - b2f(hr));
        unsigned short hm = f2b(ci);
        xbh[col][2 * n + 1] = hm; xbl[col][2 * n + 1] = f2b(ci - b2f(hm));
        float nr = fmaf(lTr, cr, fr); nr = fmaf(-lTi, ci, nr);
        float ni = fmaf(lTr, ci, fi); ni = fmaf(lTi, cr, ni);
        cr = nr; ci = ni;
      }
    }
    __syncthreads();
    // ---- W-GEMM (carry contribution), accumulate; gelu; write y bf16 ----
#pragma unroll
    for (int kk = 0; kk < 2; ++kk) {
      bf16x8 ah = *(const bf16x8*)&Wh[(rt << 4) + lrow][(kk << 5) + lk8];
      bf16x8 al = *(const bf16x8*)&Wl[(rt << 4) + lrow][(kk << 5) + lk8];
#pragma unroll
      for (int ct = 0; ct < 4; ++ct) {
        int col = (((cg << 2) + ct) << 4) + lrow;
        bf16x8 bh = *(const bf16x8*)&xbh[col][(kk << 5) + lk8];
        bf16x8 bl = *(const bf16x8*)&xbl[col][(kk << 5) + lk8];
        acc[ct] = __builtin_amdgcn_mfma_f32_16x16x32_bf16(ah, bh, acc[ct], 0, 0, 0);
        acc[ct] = __builtin_amdgcn_mfma_f32_16x16x32_bf16(ah, bl, acc[ct], 0, 0, 0);
        acc[ct] = __builtin_amdgcn_mfma_f32_16x16x32_bf16(al, bh, acc[ct], 0, 0, 0);
      }
    }
#pragma unroll
    for (int ct = 0; ct < 4; ++ct) {
      int colg = (half << 8) + (((cg << 2) + ct) << 4) + lrow;
      ushort4 o;
      o.x = f2b(gelu_exact(acc[ct][0]));
      o.y = f2b(gelu_exact(acc[ct][1]));
      o.z = f2b(gelu_exact(acc[ct][2]));
      o.w = f2b(gelu_exact(acc[ct][3]));
      *(ushort4*)(yloc + (size_t)h * (B_SZ * L_SZ) + (size_t)colg * 64 + (rt << 4) + rsub) = o;
    }
  }
}

// ---------------- post: yt copy + GLU + LN (yt XOR-swizzled) ----------------
__launch_bounds__(1024, 4)
__global__ void k_layer2(float* __restrict__ hbuf, const unsigned short* __restrict__ yloc,
                         const unsigned short* __restrict__ wbf,
                         const float* __restrict__ b_out,
                         const float* __restrict__ ln_g, const float* __restrict__ ln_b,
                         float* __restrict__ pooledPart, int last) {
  __shared__ __align__(16) unsigned short yt[TC * YROW];
  __shared__ float part[TC][16][2];
  __shared__ float stats[TC][2];
  int tid = threadIdx.x;
  int b = blockIdx.x >> 5;
  int c = blockIdx.x & 31;
  int l0 = c << 6;

  // ---- fill: yloc (already gelu'd) -> yt transpose copy ----
  {
    int h = tid >> 2, q = tid & 3;
    const unsigned short* yp2 = yloc + (size_t)h * (B_SZ * L_SZ) + b * L_SZ + l0 + (q << 4);
#pragma unroll
    for (int jj = 0; jj < 16; jj += 4) {
      ushort4 yv = *(const ushort4*)(yp2 + jj);
      int jb = (q << 4) + jj;
      yt[yswz(jb + 0, h)] = yv.x;
      yt[yswz(jb + 1, h)] = yv.y;
      yt[yswz(jb + 2, h)] = yv.z;
      yt[yswz(jb + 3, h)] = yv.w;
    }
  }
  __syncthreads();
  // ---- GLU: 1x1 conv via MFMA; z -> yt ----
  {
    int w = tid >> 6, lane = tid & 63;
    int lrow = lane & 15, lk8 = (lane >> 4) << 3;
    f32x4 accA[4], accG[4];
    f32x4 zed = {0.f, 0.f, 0.f, 0.f};
#pragma unroll
    for (int jt = 0; jt < 4; ++jt) { accA[jt] = zed; accG[jt] = zed; }
    const unsigned short* wA = wbf + ((w << 4) + lrow) * H_SZ;
    const unsigned short* wG = wA + 256 * H_SZ;
#pragma unroll
    for (int k0 = 0; k0 < H_SZ; k0 += 32) {
      bf16x8 a0 = *(const bf16x8*)(wA + k0 + lk8);
      bf16x8 a1 = *(const bf16x8*)(wG + k0 + lk8);
#pragma unroll
      for (int jt = 0; jt < 4; ++jt) {
        bf16x8 bb = *(const bf16x8*)&yt[yswz((jt << 4) + lrow, k0 + lk8)];
        accA[jt] = __builtin_amdgcn_mfma_f32_16x16x32_bf16(a0, bb, accA[jt], 0, 0, 0);
        accG[jt] = __builtin_amdgcn_mfma_f32_16x16x32_bf16(a1, bb, accG[jt], 0, 0, 0);
      }
    }
    __syncthreads();  // all y reads done before overwrite with z
    int rbase = (lane >> 4) << 2;
    float bA[4], bG[4];
#pragma unroll
    for (int r = 0; r < 4; ++r) {
      bA[r] = b_out[(w << 4) + rbase + r];
      bG[r] = b_out[256 + (w << 4) + rbase + r];
    }
#pragma unroll
    for (int jt = 0; jt < 4; ++jt) {
      ushort4 o;
      float a0 = accA[jt][0] + bA[0], g0 = accG[jt][0] + bG[0];
      float a1 = accA[jt][1] + bA[1], g1 = accG[jt][1] + bG[1];
      float a2 = accA[jt][2] + bA[2], g2 = accG[jt][2] + bG[2];
      float a3 = accA[jt][3] + bA[3], g3 = accG[jt][3] + bG[3];
      o.x = f2b(a0 / (1.f + expf(-g0)));
      o.y = f2b(a1 / (1.f + expf(-g1)));
      o.z = f2b(a2 / (1.f + expf(-g2)));
      o.w = f2b(a3 / (1.f + expf(-g3)));
      *(ushort4*)&yt[yswz((jt << 4) + lrow, (w << 4) + rbase)] = o;
    }
  }
  __syncthreads();
  // ---- LN stats; v = z + residual ----
  int j = tid & 63, hg = tid >> 6;
  float vreg[16];
  {
    const float* xc = hbuf + (b * H_SZ + (hg << 4)) * L_SZ + l0 + j;
    float s = 0.f, sq = 0.f;
    ushort4 za = *(const ushort4*)&yt[yswz(j, (hg << 4) + 0)];
    ushort4 zb = *(const ushort4*)&yt[yswz(j, (hg << 4) + 4)];
    ushort4 zc = *(const ushort4*)&yt[yswz(j, (hg << 4) + 8)];
    ushort4 zd = *(const ushort4*)&yt[yswz(j, (hg << 4) + 12)];
    unsigned short zz[16] = {za.x, za.y, za.z, za.w, zb.x, zb.y, zb.z, zb.w,
                             zc.x, zc.y, zc.z, zc.w, zd.x, zd.y, zd.z, zd.w};
#pragma unroll
    for (int k = 0; k < 16; ++k) {
      float v = b2f(zz[k]) + xc[(size_t)k * L_SZ];
      vreg[k] = v;
      s += v; sq = fmaf(v, v, sq);
    }
    part[j][hg][0] = s; part[j][hg][1] = sq;
  }
  __syncthreads();
  if (tid < TC) {
    float s = 0.f, sq = 0.f;
#pragma unroll
    for (int g = 0; g < 16; ++g) { s += part[tid][g][0]; sq += part[tid][g][1]; }
    float mu = s * (1.f / 256.f);
    float var = sq * (1.f / 256.f) - mu * mu;
    stats[tid][0] = mu;
    stats[tid][1] = rsqrtf(var + 1e-5f);
  }
  __syncthreads();
  {
    float mu = stats[j][0], rs = stats[j][1];
    if (!last) {
      float* xo = hbuf + (b * H_SZ + (hg << 4)) * L_SZ + l0 + j;
#pragma unroll
      for (int k = 0; k < 16; ++k) {
        int hh = (hg << 4) + k;
        xo[(size_t)k * L_SZ] = (vreg[k] - mu) * rs * ln_g[hh] + ln_b[hh];
      }
    } else {
#pragma unroll
      for (int k = 0; k < 16; ++k) {
        int hh = (hg << 4) + k;
        yt[yswz(j, hh)] = f2b((vreg[k] - mu) * rs * ln_g[hh] + ln_b[hh]);
      }
      __syncthreads();
      if (tid < H_SZ) {
        float s = 0.f;
        for (int jj = 0; jj < TC; ++jj) s += b2f(yt[yswz(jj, tid)]);
        pooledPart[(((b << 5) + c) << 8) + tid] = s;
      }
    }
  }
}

// ---------------- pool: reduce 32 chunk-partials per (b,h) ----------------
__global__ void k_pool(const float* __restrict__ pooledPart, float* __restrict__ P) {
  int b = blockIdx.x, hh = threadIdx.x;
  float s = 0.f;
#pragma unroll
  for (int cpart = 0; cpart < 32; ++cpart)
    s += pooledPart[(((b << 5) + cpart) << 8) + hh];
  P[(b << 8) + hh] = s * (1.f / 2048.f);
}

// ---------------- decoder MLP: one block per batch row ----------------
__global__ void k_dec(const float* __restrict__ P,
                      const float* __restrict__ w1, const float* __restrict__ b1,
                      const float* __restrict__ w2, const float* __restrict__ b2,
                      const float* __restrict__ w3, const float* __restrict__ b3,
                      float* __restrict__ out) {
  __shared__ float Pr[256];
  __shared__ float O1[128];
  __shared__ float O2[64];
  int b = blockIdx.x, tid = threadIdx.x;
  Pr[tid] = P[(b << 8) + tid];
  __syncthreads();
  if (tid < 128) {
    float acc = b1[tid];
    for (int d = 0; d < 256; ++d) acc = fmaf(Pr[d], w1[(d << 7) + tid], acc);
    O1[tid] = fmaxf(acc, 0.f);
  }
  __syncthreads();
  if (tid < 64) {
    float acc = b2[tid];
    for (int d = 0; d < 128; ++d) acc = fmaf(O1[d], w2[(d << 6) + tid], acc);
    O2[tid] = fmaxf(acc, 0.f);
  }
  __syncthreads();
  if (tid < 32) {
    float acc = b3[tid];
    for (int d = 0; d < 64; ++d) acc = fmaf(O2[d], w3[(d << 5) + tid], acc);
    out[(b << 5) + tid] = acc;
  }
}

extern "C" void kernel_launch(void* const* d_in, const int* in_sizes, int n_in,
                              void* d_out, int out_size, void* d_ws, size_t ws_size,
                              hipStream_t stream) {
  const float* x          = (const float*)d_in[0];
  const float* enc_w      = (const float*)d_in[1];
  const float* enc_b      = (const float*)d_in[2];
  const float* log_dt     = (const float*)d_in[3];
  const float* C_re       = (const float*)d_in[4];
  const float* C_im       = (const float*)d_in[5];
  const float* log_A_real = (const float*)d_in[6];
  const float* A_imag     = (const float*)d_in[7];
  const float* D_skip     = (const float*)d_in[8];
  const float* w_out      = (const float*)d_in[9];
  const float* b_out      = (const float*)d_in[10];
  const float* ln_g       = (const float*)d_in[11];
  const float* ln_b       = (const float*)d_in[12];
  const float* dw1        = (const float*)d_in[13];
  const float* db1        = (const float*)d_in[14];
  const float* dw2        = (const float*)d_in[15];
  const float* db2        = (const float*)d_in[16];
  const float* dw3        = (const float*)d_in[17];
  const float* db3        = (const float*)d_in[18];

  char* ws = (char*)d_ws;
  float* hbuf = (float*)ws;                                  // 33,554,432 B
  unsigned short* yloc = (unsigned short*)(ws + 33554432);   // 16,777,216 B (bf16)
  unsigned short* wbf = (unsigned short*)(ws + 50331648);    //  1,048,576 B
  float* par = (float*)(ws + 51380224);                      //  1,048,576 B
  float* pooledPart = (float*)(ws + 52428800);               //    524,288 B
  float* P = (float*)(ws + 52953088);                        //     16,384 B

  k_encoder<<<512, 512, 0, stream>>>(x, enc_w, enc_b, hbuf);
  k_cvtw<<<2048, 256, 0, stream>>>(w_out, wbf, NL * 512 * H_SZ);
  k_params<<<128, 256, 0, stream>>>(log_dt, log_A_real, A_imag, C_re, C_im, par);
  const size_t PAR_STRIDE = (size_t)H_SZ * NH * 8;
  for (int i = 0; i < NL; ++i) {
    const float* pari = par + i * PAR_STRIDE;
    k_ssm<<<256, 1024, 0, stream>>>(hbuf, pari, D_skip + i * H_SZ, yloc);
    k_layer2<<<512, 1024, 0, stream>>>(hbuf, yloc,
                                       wbf + i * 512 * H_SZ, b_out + i * 512,
                                       ln_g + i * H_SZ, ln_b + i * H_SZ,
                                       pooledPart, (i == NL - 1) ? 1 : 0);
  }
  k_pool<<<16, 256, 0, stream>>>(pooledPart, P);
  k_dec<<<16, 256, 0, stream>>>(P, dw1, db1, dw2, db2, dw3, db3, (float*)d_out);
}

// Round 19
// 303.652 us; speedup vs baseline: 1.1237x; 1.0129x over previous
//
#include <hip/hip_runtime.h>

#define B_SZ 16
#define L_SZ 2048
#define DIN 64
#define H_SZ 256
#define NH 32
#define NL 4
#define TC 64
#define NTC 32
#define YROW (H_SZ + 8)

typedef __attribute__((ext_vector_type(8))) __bf16 bf16x8;
typedef __attribute__((ext_vector_type(4))) float f32x4;

__device__ __forceinline__ unsigned short f2b(float f) {
  unsigned int u = __builtin_bit_cast(unsigned int, f);
  unsigned int r = u + 0x7fffu + ((u >> 16) & 1u);  // RNE (no NaN inputs here)
  return (unsigned short)(r >> 16);
}
__device__ __forceinline__ float b2f(unsigned short u) {
  unsigned int v = ((unsigned int)u) << 16;
  return __builtin_bit_cast(float, v);
}
__device__ __forceinline__ float gelu_exact(float v) {
  return 0.5f * v * (1.f + erff(v * 0.70710678118654752f));
}
// 16B-granule XOR swizzle for yt
__device__ __forceinline__ int yswz(int row, int col) {
  return (row * YROW + col) ^ (((row >> 3) & 7) << 3);
}

// ---------------- encoder as compensated MFMA GEMM ----------------
__launch_bounds__(512, 4)
__global__ void k_encoder(const float* __restrict__ x, const float* __restrict__ w,
                          const float* __restrict__ bias, float* __restrict__ hbuf) {
  __shared__ __align__(16) unsigned short Wh[128][72];
  __shared__ __align__(16) unsigned short Wl[128][72];
  __shared__ __align__(16) unsigned short xh[128][72];
  __shared__ __align__(16) unsigned short xl[128][72];
  int tid = threadIdx.x;
  int blk = blockIdx.x;           // b(4b) lt(4b) hh(1b)
  int b = blk >> 5;
  int lt = (blk >> 1) & 15;
  int hh = blk & 1;

#pragma unroll
  for (int i = 0; i < 16; ++i) {
    int flat = i * 512 + tid;
    int d = flat >> 7, hl = flat & 127;
    float v = w[d * H_SZ + (hh << 7) + hl];
    unsigned short hv = f2b(v);
    Wh[hl][d] = hv; Wl[hl][d] = f2b(v - b2f(hv));
  }
  {
    int l = tid >> 2, d0 = (tid & 3) << 4;
    const float* src = x + ((size_t)(b * L_SZ + (lt << 7) + l) << 6) + d0;
    unsigned short* dh = &xh[l][d0];
    unsigned short* dl = &xl[l][d0];
#pragma unroll
    for (int jj = 0; jj < 4; ++jj) {
      float4 v = *(const float4*)(src + jj * 4);
      unsigned short h0 = f2b(v.x); dh[jj * 4 + 0] = h0; dl[jj * 4 + 0] = f2b(v.x - b2f(h0));
      unsigned short h1 = f2b(v.y); dh[jj * 4 + 1] = h1; dl[jj * 4 + 1] = f2b(v.y - b2f(h1));
      unsigned short h2 = f2b(v.z); dh[jj * 4 + 2] = h2; dl[jj * 4 + 2] = f2b(v.z - b2f(h2));
      unsigned short h3 = f2b(v.w); dh[jj * 4 + 3] = h3; dl[jj * 4 + 3] = f2b(v.w - b2f(h3));
    }
  }
  __syncthreads();

  int wv = tid >> 6, lane = tid & 63;
  int lrow = lane & 15, lk8 = (lane >> 4) << 3;
  int rsub = (lane >> 4) << 2;
  f32x4 acc[8];
#pragma unroll
  for (int ct = 0; ct < 8; ++ct) acc[ct] = (f32x4){0.f, 0.f, 0.f, 0.f};
  __builtin_amdgcn_s_setprio(1);
#pragma unroll
  for (int kk = 0; kk < 2; ++kk) {
    bf16x8 ah = *(const bf16x8*)&Wh[(wv << 4) + lrow][(kk << 5) + lk8];
    bf16x8 al = *(const bf16x8*)&Wl[(wv << 4) + lrow][(kk << 5) + lk8];
#pragma unroll
    for (int ct = 0; ct < 8; ++ct) {
      bf16x8 bh = *(const bf16x8*)&xh[(ct << 4) + lrow][(kk << 5) + lk8];
      bf16x8 bl = *(const bf16x8*)&xl[(ct << 4) + lrow][(kk << 5) + lk8];
      acc[ct] = __builtin_amdgcn_mfma_f32_16x16x32_bf16(ah, bh, acc[ct], 0, 0, 0);
      acc[ct] = __builtin_amdgcn_mfma_f32_16x16x32_bf16(ah, bl, acc[ct], 0, 0, 0);
      acc[ct] = __builtin_amdgcn_mfma_f32_16x16x32_bf16(al, bh, acc[ct], 0, 0, 0);
    }
  }
  __builtin_amdgcn_s_setprio(0);
  float bi[4];
#pragma unroll
  for (int r = 0; r < 4; ++r) bi[r] = bias[(hh << 7) + (wv << 4) + rsub + r];
#pragma unroll
  for (int ct = 0; ct < 8; ++ct) {
    int lglob = (lt << 7) + (ct << 4) + lrow;
#pragma unroll
    for (int r = 0; r < 4; ++r) {
      int hglob = (hh << 7) + (wv << 4) + rsub + r;
      hbuf[((size_t)(b * H_SZ + hglob) << 11) + lglob] = acc[ct][r] + bi[r];
    }
  }
}

// ---------------- convert w_out to bf16 ----------------
__global__ void k_cvtw(const float* __restrict__ w, unsigned short* __restrict__ wbf, int n) {
  int i = blockIdx.x * 256 + threadIdx.x;
  if (i < n) wbf[i] = f2b(w[i]);
}

// ---------------- precompute per-state params: lr, li, c2r, c2i, lTr, lTi ----------------
__global__ void k_params(const float* __restrict__ log_dt, const float* __restrict__ log_A_real,
                         const float* __restrict__ A_imag, const float* __restrict__ C_re,
                         const float* __restrict__ C_im, float* __restrict__ par) {
  int id = blockIdx.x * 256 + threadIdx.x;  // i*8192 + h*32 + n
  if (id >= NL * H_SZ * NH) return;
  int i = id >> 13;
  int hn = id & 8191;
  int h = hn >> 5;
  float dt = expf(log_dt[i * H_SZ + h]);
  float Ar = -expf(log_A_real[(size_t)i * H_SZ * NH + hn]);
  float Ai = A_imag[(size_t)i * H_SZ * NH + hn];
  float dr = dt * Ar, di = dt * Ai;
  float e = expf(dr), sn, cs;
  sincosf(di, &sn, &cs);
  float lr = e * cs, li = e * sn;
  float eT = expf((float)TC * dr), snT, csT;
  sincosf((float)TC * di, &snT, &csT);
  float Cr = C_re[(size_t)i * H_SZ * NH + hn], Ci = C_im[(size_t)i * H_SZ * NH + hn];
  float wr = lr - 1.f, wi = li;
  float pr = Cr * wr - Ci * wi;
  float pi = Cr * wi + Ci * wr;
  float inv = 2.f / fmaf(Ar, Ar, Ai * Ai);
  float4* p = (float4*)(par + (size_t)id * 8);
  p[0] = make_float4(lr, li, (pr * Ar + pi * Ai) * inv, (pi * Ar - pr * Ai) * inv);
  p[1] = make_float4(eT * csT, eT * snT, 0.f, 0.f);
}

// ---------------- merged SSM kernel (1024 thr, 16 waves): finals+prefix in LDS+conv+GELU ----
__launch_bounds__(1024, 4)
__global__ void k_ssm(const float* __restrict__ hbuf, const float* __restrict__ par,
                      const float* __restrict__ D_skip, unsigned short* __restrict__ yloc) {
  __shared__ __align__(16) unsigned short xbh[256][72];
  __shared__ __align__(16) unsigned short xbl[256][72];
  __shared__ __align__(16) unsigned short Uh[64][72];
  __shared__ __align__(16) unsigned short Ul[64][72];
  __shared__ __align__(16) unsigned short Th[64][72];
  __shared__ __align__(16) unsigned short Tl[64][72];
  __shared__ __align__(16) unsigned short Wh[64][72];
  __shared__ __align__(16) unsigned short Wl[64][72];
  __shared__ float Kc[64];
  int tid = threadIdx.x;
  int h = blockIdx.x;
  float* Wm = (float*)&xbh[0][0];  // [64][66] f32 scratch, dead before x staging

  if (tid < 64) {
    int n = tid >> 1, q = tid & 1;
    const float* pb = par + (size_t)(h * NH + n) * 8;
    float lr = pb[0], li = pb[1], c2r = pb[2], c2i = pb[3];
    float pr = lr, pi = li;  // lam^1
    if (q) {                 // lam^33
      float sr = lr, si = li;
#pragma unroll
      for (int t = 0; t < 5; ++t) { float nr2 = sr * sr - si * si; si = 2.f * sr * si; sr = nr2; }
      pr = sr * lr - si * li; pi = sr * li + si * lr;
    }
    int p = q << 5;
    for (int s = 0; s < 32; ++s, ++p) {
      Wm[p * 66 + 2 * n] = c2r * pr - c2i * pi;
      Wm[p * 66 + 2 * n + 1] = -(c2r * pi + c2i * pr);
      float nr2 = pr * lr - pi * li;
      pi = pr * li + pi * lr;
      pr = nr2;
    }
  }
  __syncthreads();
  if (tid < 64) {
    float kv = 0.f;
    if (tid == 0) {
      for (int n = 0; n < 32; ++n) kv += par[(size_t)(h * NH + n) * 8 + 2];
    } else {
      for (int n = 0; n < 32; ++n) kv += Wm[(tid - 1) * 66 + 2 * n];
    }
    Kc[tid] = kv;
  }
  {
    int base = tid * 4;          // 1024 thr x 4 = 4096 = 64x64
    int row = base >> 6, col0 = base & 63;
#pragma unroll
    for (int e = 0; e < 4; ++e) {
      float v = Wm[row * 66 + col0 + e];
      unsigned short hv = f2b(v);
      Wh[row][col0 + e] = hv; Wl[row][col0 + e] = f2b(v - b2f(hv));
    }
  }
  __syncthreads();
  {
    int base = tid * 4;
    int row = base >> 6, col0 = base & 63;
#pragma unroll
    for (int e = 0; e < 4; ++e) {
      int col = col0 + e;
      float v = (col <= row) ? Kc[row - col] : 0.f;
      unsigned short hv = f2b(v);
      Th[row][col] = hv; Tl[row][col] = f2b(v - b2f(hv));
    }
  }
  if (tid < 64) {
    int n = tid >> 1, q = tid & 1;
    const float* pb = par + (size_t)(h * NH + n) * 8;
    float lr = pb[0], li = pb[1];
    float pr = 1.f, pi = 0.f;
    if (q) {
      float sr = lr, si = li;
#pragma unroll
      for (int t = 0; t < 5; ++t) { float nr2 = sr * sr - si * si; si = 2.f * sr * si; sr = nr2; }
      pr = sr; pi = si;
    }
    int p = q << 5;
    for (int s = 0; s < 32; ++s, ++p) {
      int col = 63 - p;
      unsigned short hr = f2b(pr);
      Uh[2 * n][col] = hr; Ul[2 * n][col] = f2b(pr - b2f(hr));
      unsigned short hm = f2b(pi);
      Uh[2 * n + 1][col] = hm; Ul[2 * n + 1][col] = f2b(pi - b2f(hm));
      float nr2 = pr * lr - pi * li;
      pi = pr * li + pi * lr;
      pr = nr2;
    }
  }

  int wv = tid >> 6, lane = tid & 63;
  int lrow = lane & 15, lk8 = (lane >> 4) << 3;
  int rt = wv >> 2;                // row-tile 0..3
  int cg = wv & 3;                 // col-group 0..3 (4 col-tiles each)
  int rsub = (lane >> 4) << 2;
  float Dh = D_skip[h];

  for (int half = 0; half < 2; ++half) {
    __syncthreads();  // matrices ready / previous half's svec reads done
    // ---- stage x hi/lo (1024 thr: 16 elems each) ----
    {
      int colh = tid >> 2, j0 = (tid & 3) << 4;
      int b = (half << 3) + (colh >> 5), c = colh & 31;
      const float* src = hbuf + ((size_t)(b * H_SZ + h) << 11) + (c << 6) + j0;
      unsigned short* dh = &xbh[colh][j0];
      unsigned short* dl = &xbl[colh][j0];
#pragma unroll
      for (int jj = 0; jj < 4; ++jj) {
        float4 v = *(const float4*)(src + jj * 4);
        unsigned short h0 = f2b(v.x); dh[jj * 4 + 0] = h0; dl[jj * 4 + 0] = f2b(v.x - b2f(h0));
        unsigned short h1 = f2b(v.y); dh[jj * 4 + 1] = h1; dl[jj * 4 + 1] = f2b(v.y - b2f(h1));
        unsigned short h2 = f2b(v.z); dh[jj * 4 + 2] = h2; dl[jj * 4 + 2] = f2b(v.z - b2f(h2));
        unsigned short h3 = f2b(v.w); dh[jj * 4 + 3] = h3; dl[jj * 4 + 3] = f2b(v.w - b2f(h3));
      }
    }
    __syncthreads();
    // ---- U-GEMM: chunk finals (keep in registers) ----
    f32x4 uacc[4];
#pragma unroll
    for (int ct = 0; ct < 4; ++ct) uacc[ct] = (f32x4){0.f, 0.f, 0.f, 0.f};
    __builtin_amdgcn_s_setprio(1);
#pragma unroll
    for (int kk = 0; kk < 2; ++kk) {
      bf16x8 ah = *(const bf16x8*)&Uh[(rt << 4) + lrow][(kk << 5) + lk8];
      bf16x8 al = *(const bf16x8*)&Ul[(rt << 4) + lrow][(kk << 5) + lk8];
#pragma unroll
      for (int ct = 0; ct < 4; ++ct) {
        int col = (((cg << 2) + ct) << 4) + lrow;
        bf16x8 bh = *(const bf16x8*)&xbh[col][(kk << 5) + lk8];
        bf16x8 bl = *(const bf16x8*)&xbl[col][(kk << 5) + lk8];
        uacc[ct] = __builtin_amdgcn_mfma_f32_16x16x32_bf16(ah, bh, uacc[ct], 0, 0, 0);
        uacc[ct] = __builtin_amdgcn_mfma_f32_16x16x32_bf16(ah, bl, uacc[ct], 0, 0, 0);
        uacc[ct] = __builtin_amdgcn_mfma_f32_16x16x32_bf16(al, bh, uacc[ct], 0, 0, 0);
      }
    }
    // ---- T-GEMM (x still staged) ----
    f32x4 acc[4];
#pragma unroll
    for (int ct = 0; ct < 4; ++ct) acc[ct] = (f32x4){0.f, 0.f, 0.f, 0.f};
#pragma unroll
    for (int kk = 0; kk < 2; ++kk) {
      bf16x8 ah = *(const bf16x8*)&Th[(rt << 4) + lrow][(kk << 5) + lk8];
      bf16x8 al = *(const bf16x8*)&Tl[(rt << 4) + lrow][(kk << 5) + lk8];
#pragma unroll
      for (int ct = 0; ct < 4; ++ct) {
        int col = (((cg << 2) + ct) << 4) + lrow;
        bf16x8 bh = *(const bf16x8*)&xbh[col][(kk << 5) + lk8];
        bf16x8 bl = *(const bf16x8*)&xbl[col][(kk << 5) + lk8];
        acc[ct] = __builtin_amdgcn_mfma_f32_16x16x32_bf16(ah, bh, acc[ct], 0, 0, 0);
        acc[ct] = __builtin_amdgcn_mfma_f32_16x16x32_bf16(ah, bl, acc[ct], 0, 0, 0);
        acc[ct] = __builtin_amdgcn_mfma_f32_16x16x32_bf16(al, bh, acc[ct], 0, 0, 0);
      }
    }
    __builtin_amdgcn_s_setprio(0);
    // ---- add D-skip term while x is still staged (x = hi + lo, ~exact) ----
    {
#pragma unroll
      for (int ct = 0; ct < 4; ++ct) {
        int col = (((cg << 2) + ct) << 4) + lrow;
        int row = (rt << 4) + rsub;
        ushort4 xh4 = *(const ushort4*)&xbh[col][row];
        ushort4 xl4 = *(const ushort4*)&xbl[col][row];
        acc[ct][0] = fmaf(Dh, b2f(xh4.x) + b2f(xl4.x), acc[ct][0]);
        acc[ct][1] = fmaf(Dh, b2f(xh4.y) + b2f(xl4.y), acc[ct][1]);
        acc[ct][2] = fmaf(Dh, b2f(xh4.z) + b2f(xl4.z), acc[ct][2]);
        acc[ct][3] = fmaf(Dh, b2f(xh4.w) + b2f(xl4.w), acc[ct][3]);
      }
    }
    __syncthreads();  // all x reads done; xbh/xbl reusable
    // ---- write finals (hi/lo bf16) into xbh/xbl in svec layout [col][2n] ----
    {
      int n0 = (rt << 3) + ((lane >> 4) << 1);
#pragma unroll
      for (int ct = 0; ct < 4; ++ct) {
        int colh = (((cg << 2) + ct) << 4) + lrow;
        ushort4 oh, ol;
        oh.x = f2b(uacc[ct][0]); ol.x = f2b(uacc[ct][0] - b2f(oh.x));
        oh.y = f2b(uacc[ct][1]); ol.y = f2b(uacc[ct][1] - b2f(oh.y));
        oh.z = f2b(uacc[ct][2]); ol.z = f2b(uacc[ct][2] - b2f(oh.z));
        oh.w = f2b(uacc[ct][3]); ol.w = f2b(uacc[ct][3] - b2f(oh.w));
        *(ushort4*)&xbh[colh][2 * n0] = oh;
        *(ushort4*)&xbl[colh][2 * n0] = ol;
      }
    }
    __syncthreads();
    // ---- exclusive prefix in LDS: thread=(b,n); in-place finals -> carries ----
    if (tid < 256) {
      int bb = tid >> 5, n = tid & 31;
      const float* pb = par + (size_t)(h * NH + n) * 8;
      float lTr = pb[4], lTi = pb[5];
      float cr = 0.f, ci = 0.f;
      for (int c = 0; c < NTC; ++c) {
        int col = (bb << 5) + c;
        float fr = b2f(xbh[col][2 * n]) + b2f(xbl[col][2 * n]);
        float fi = b2f(xbh[col][2 * n + 1]) + b2f(xbl[col][2 * n + 1]);
        unsigned short hr = f2b(cr);
        xbh[col][2 * n] = hr; xbl[col][2 * n] = f2b(cr - b2f(hr));
        unsigned short hm = f2b(ci);
        xbh[col][2 * n + 1] = hm; xbl[col][2 * n + 1] = f2b(ci - b2f(hm));
        float nr = fmaf(lTr, cr, fr); nr = fmaf(-lTi, ci, nr);
        float ni = fmaf(lTr, ci, fi); ni = fmaf(lTi, cr, ni);
        cr = nr; ci = ni;
      }
    }
    __syncthreads();
    // ---- W-GEMM (carry contribution), accumulate; gelu; write y bf16 ----
    __builtin_amdgcn_s_setprio(1);
#pragma unroll
    for (int kk = 0; kk < 2; ++kk) {
      bf16x8 ah = *(const bf16x8*)&Wh[(rt << 4) + lrow][(kk << 5) + lk8];
      bf16x8 al = *(const bf16x8*)&Wl[(rt << 4) + lrow][(kk << 5) + lk8];
#pragma unroll
      for (int ct = 0; ct < 4; ++ct) {
        int col = (((cg << 2) + ct) << 4) + lrow;
        bf16x8 bh = *(const bf16x8*)&xbh[col][(kk << 5) + lk8];
        bf16x8 bl = *(const bf16x8*)&xbl[col][(kk << 5) + lk8];
        acc[ct] = __builtin_amdgcn_mfma_f32_16x16x32_bf16(ah, bh, acc[ct], 0, 0, 0);
        acc[ct] = __builtin_amdgcn_mfma_f32_16x16x32_bf16(ah, bl, acc[ct], 0, 0, 0);
        acc[ct] = __builtin_amdgcn_mfma_f32_16x16x32_bf16(al, bh, acc[ct], 0, 0, 0);
      }
    }
    __builtin_amdgcn_s_setprio(0);
#pragma unroll
    for (int ct = 0; ct < 4; ++ct) {
      int colg = (half << 8) + (((cg << 2) + ct) << 4) + lrow;
      ushort4 o;
      o.x = f2b(gelu_exact(acc[ct][0]));
      o.y = f2b(gelu_exact(acc[ct][1]));
      o.z = f2b(gelu_exact(acc[ct][2]));
      o.w = f2b(gelu_exact(acc[ct][3]));
      *(ushort4*)(yloc + (size_t)h * (B_SZ * L_SZ) + (size_t)colg * 64 + (rt << 4) + rsub) = o;
    }
  }
}

// ---------------- post: yt copy + GLU + LN (yt XOR-swizzled) ----------------
__launch_bounds__(1024, 4)
__global__ void k_layer2(float* __restrict__ hbuf, const unsigned short* __restrict__ yloc,
                         const unsigned short* __restrict__ wbf,
                         const float* __restrict__ b_out,
                         const float* __restrict__ ln_g, const float* __restrict__ ln_b,
                         float* __restrict__ pooledPart, int last) {
  __shared__ __align__(16) unsigned short yt[TC * YROW];
  __shared__ float part[TC][16][2];
  __shared__ float stats[TC][2];
  int tid = threadIdx.x;
  int b = blockIdx.x >> 5;
  int c = blockIdx.x & 31;
  int l0 = c << 6;

  // ---- fill: yloc (already gelu'd) -> yt transpose copy ----
  {
    int h = tid >> 2, q = tid & 3;
    const unsigned short* yp2 = yloc + (size_t)h * (B_SZ * L_SZ) + b * L_SZ + l0 + (q << 4);
#pragma unroll
    for (int jj = 0; jj < 16; jj += 4) {
      ushort4 yv = *(const ushort4*)(yp2 + jj);
      int jb = (q << 4) + jj;
      yt[yswz(jb + 0, h)] = yv.x;
      yt[yswz(jb + 1, h)] = yv.y;
      yt[yswz(jb + 2, h)] = yv.z;
      yt[yswz(jb + 3, h)] = yv.w;
    }
  }
  __syncthreads();
  // ---- GLU: 1x1 conv via MFMA; z -> yt ----
  {
    int w = tid >> 6, lane = tid & 63;
    int lrow = lane & 15, lk8 = (lane >> 4) << 3;
    f32x4 accA[4], accG[4];
    f32x4 zed = {0.f, 0.f, 0.f, 0.f};
#pragma unroll
    for (int jt = 0; jt < 4; ++jt) { accA[jt] = zed; accG[jt] = zed; }
    const unsigned short* wA = wbf + ((w << 4) + lrow) * H_SZ;
    const unsigned short* wG = wA + 256 * H_SZ;
    __builtin_amdgcn_s_setprio(1);
#pragma unroll
    for (int k0 = 0; k0 < H_SZ; k0 += 32) {
      bf16x8 a0 = *(const bf16x8*)(wA + k0 + lk8);
      bf16x8 a1 = *(const bf16x8*)(wG + k0 + lk8);
#pragma unroll
      for (int jt = 0; jt < 4; ++jt) {
        bf16x8 bb = *(const bf16x8*)&yt[yswz((jt << 4) + lrow, k0 + lk8)];
        accA[jt] = __builtin_amdgcn_mfma_f32_16x16x32_bf16(a0, bb, accA[jt], 0, 0, 0);
        accG[jt] = __builtin_amdgcn_mfma_f32_16x16x32_bf16(a1, bb, accG[jt], 0, 0, 0);
      }
    }
    __builtin_amdgcn_s_setprio(0);
    __syncthreads();  // all y reads done before overwrite with z
    int rbase = (lane >> 4) << 2;
    float bA[4], bG[4];
#pragma unroll
    for (int r = 0; r < 4; ++r) {
      bA[r] = b_out[(w << 4) + rbase + r];
      bG[r] = b_out[256 + (w << 4) + rbase + r];
    }
#pragma unroll
    for (int jt = 0; jt < 4; ++jt) {
      ushort4 o;
      float a0 = accA[jt][0] + bA[0], g0 = accG[jt][0] + bG[0];
      float a1 = accA[jt][1] + bA[1], g1 = accG[jt][1] + bG[1];
      float a2 = accA[jt][2] + bA[2], g2 = accG[jt][2] + bG[2];
      float a3 = accA[jt][3] + bA[3], g3 = accG[jt][3] + bG[3];
      o.x = f2b(a0 / (1.f + expf(-g0)));
      o.y = f2b(a1 / (1.f + expf(-g1)));
      o.z = f2b(a2 / (1.f + expf(-g2)));
      o.w = f2b(a3 / (1.f + expf(-g3)));
      *(ushort4*)&yt[yswz((jt << 4) + lrow, (w << 4) + rbase)] = o;
    }
  }
  __syncthreads();
  // ---- LN stats; v = z + residual ----
  int j = tid & 63, hg = tid >> 6;
  float vreg[16];
  {
    const float* xc = hbuf + (b * H_SZ + (hg << 4)) * L_SZ + l0 + j;
    float s = 0.f, sq = 0.f;
    ushort4 za = *(const ushort4*)&yt[yswz(j, (hg << 4) + 0)];
    ushort4 zb = *(const ushort4*)&yt[yswz(j, (hg << 4) + 4)];
    ushort4 zc = *(const ushort4*)&yt[yswz(j, (hg << 4) + 8)];
    ushort4 zd = *(const ushort4*)&yt[yswz(j, (hg << 4) + 12)];
    unsigned short zz[16] = {za.x, za.y, za.z, za.w, zb.x, zb.y, zb.z, zb.w,
                             zc.x, zc.y, zc.z, zc.w, zd.x, zd.y, zd.z, zd.w};
#pragma unroll
    for (int k = 0; k < 16; ++k) {
      float v = b2f(zz[k]) + xc[(size_t)k * L_SZ];
      vreg[k] = v;
      s += v; sq = fmaf(v, v, sq);
    }
    part[j][hg][0] = s; part[j][hg][1] = sq;
  }
  __syncthreads();
  if (tid < TC) {
    float s = 0.f, sq = 0.f;
#pragma unroll
    for (int g = 0; g < 16; ++g) { s += part[tid][g][0]; sq += part[tid][g][1]; }
    float mu = s * (1.f / 256.f);
    float var = sq * (1.f / 256.f) - mu * mu;
    stats[tid][0] = mu;
    stats[tid][1] = rsqrtf(var + 1e-5f);
  }
  __syncthreads();
  {
    float mu = stats[j][0], rs = stats[j][1];
    if (!last) {
      float* xo = hbuf + (b * H_SZ + (hg << 4)) * L_SZ + l0 + j;
#pragma unroll
      for (int k = 0; k < 16; ++k) {
        int hh = (hg << 4) + k;
        xo[(size_t)k * L_SZ] = (vreg[k] - mu) * rs * ln_g[hh] + ln_b[hh];
      }
    } else {
#pragma unroll
      for (int k = 0; k < 16; ++k) {
        int hh = (hg << 4) + k;
        yt[yswz(j, hh)] = f2b((vreg[k] - mu) * rs * ln_g[hh] + ln_b[hh]);
      }
      __syncthreads();
      if (tid < H_SZ) {
        float s = 0.f;
        for (int jj = 0; jj < TC; ++jj) s += b2f(yt[yswz(jj, tid)]);
        pooledPart[(((b << 5) + c) << 8) + tid] = s;
      }
    }
  }
}

// ---------------- decoder MLP (pool fused): one block per batch row ----------------
__global__ void k_dec(const float* __restrict__ pooledPart,
                      const float* __restrict__ w1, const float* __restrict__ b1,
                      const float* __restrict__ w2, const float* __restrict__ b2,
                      const float* __restrict__ w3, const float* __restrict__ b3,
                      float* __restrict__ out) {
  __shared__ float Pr[256];
  __shared__ float O1[128];
  __shared__ float O2[64];
  int b = blockIdx.x, tid = threadIdx.x;
  {
    float s = 0.f;
#pragma unroll
    for (int cpart = 0; cpart < 32; ++cpart)
      s += pooledPart[(((b << 5) + cpart) << 8) + tid];
    Pr[tid] = s * (1.f / 2048.f);
  }
  __syncthreads();
  if (tid < 128) {
    float acc = b1[tid];
    for (int d = 0; d < 256; ++d) acc = fmaf(Pr[d], w1[(d << 7) + tid], acc);
    O1[tid] = fmaxf(acc, 0.f);
  }
  __syncthreads();
  if (tid < 64) {
    float acc = b2[tid];
    for (int d = 0; d < 128; ++d) acc = fmaf(O1[d], w2[(d << 6) + tid], acc);
    O2[tid] = fmaxf(acc, 0.f);
  }
  __syncthreads();
  if (tid < 32) {
    float acc = b3[tid];
    for (int d = 0; d < 64; ++d) acc = fmaf(O2[d], w3[(d << 5) + tid], acc);
    out[(b << 5) + tid] = acc;
  }
}

extern "C" void kernel_launch(void* const* d_in, const int* in_sizes, int n_in,
                              void* d_out, int out_size, void* d_ws, size_t ws_size,
                              hipStream_t stream) {
  const float* x          = (const float*)d_in[0];
  const float* enc_w      = (const float*)d_in[1];
  const float* enc_b      = (const float*)d_in[2];
  const float* log_dt     = (const float*)d_in[3];
  const float* C_re       = (const float*)d_in[4];
  const float* C_im       = (const float*)d_in[5];
  const float* log_A_real = (const float*)d_in[6];
  const float* A_imag     = (const float*)d_in[7];
  const float* D_skip     = (const float*)d_in[8];
  const float* w_out      = (const float*)d_in[9];
  const float* b_out      = (const float*)d_in[10];
  const float* ln_g       = (const float*)d_in[11];
  const float* ln_b       = (const float*)d_in[12];
  const float* dw1        = (const float*)d_in[13];
  const float* db1        = (const float*)d_in[14];
  const float* dw2        = (const float*)d_in[15];
  const float* db2        = (const float*)d_in[16];
  const float* dw3        = (const float*)d_in[17];
  const float* db3        = (const float*)d_in[18];

  char* ws = (char*)d_ws;
  float* hbuf = (float*)ws;                                  // 33,554,432 B
  unsigned short* yloc = (unsigned short*)(ws + 33554432);   // 16,777,216 B (bf16)
  unsigned short* wbf = (unsigned short*)(ws + 50331648);    //  1,048,576 B
  float* par = (float*)(ws + 51380224);                      //  1,048,576 B
  float* pooledPart = (float*)(ws + 52428800);               //    524,288 B

  k_encoder<<<512, 512, 0, stream>>>(x, enc_w, enc_b, hbuf);
  k_cvtw<<<2048, 256, 0, stream>>>(w_out, wbf, NL * 512 * H_SZ);
  k_params<<<128, 256, 0, stream>>>(log_dt, log_A_real, A_imag, C_re, C_im, par);
  const size_t PAR_STRIDE = (size_t)H_SZ * NH * 8;
  for (int i = 0; i < NL; ++i) {
    const float* pari = par + i * PAR_STRIDE;
    k_ssm<<<256, 1024, 0, stream>>>(hbuf, pari, D_skip + i * H_SZ, yloc);
    k_layer2<<<512, 1024, 0, stream>>>(hbuf, yloc,
                                       wbf + i * 512 * H_SZ, b_out + i * 512,
                                       ln_g + i * H_SZ, ln_b + i * H_SZ,
                                       pooledPart, (i == NL - 1) ? 1 : 0);
  }
  k_dec<<<16, 256, 0, stream>>>(pooledPart, dw1, db1, dw2, db2, dw3, db3, (float*)d_out);
}